// Round 3
// baseline (217.698 us; speedup 1.0000x reference)
//
#include <hip/hip_runtime.h>
#include <hip/hip_bf16.h>

// MHA fwd: B=2, S=2048, D=256, H=8, Dh=32.
// Outputs: out [2,2048,256] fp32, attn_mean [2,2048,2048] fp32 (concat in d_out).
//
// R2: transpose-free flash attention.
//  - attn_flash computes S^T = K.Q^T (operand swap, same loads). Its C-layout
//    (q=lane&15, key=quad*4+r) is directly a valid B-operand for O^T = V^T.P^T
//    under a key-slot permutation pi(quad*8+j) = quad*4+j | 16+quad*4+(j-4),
//    which is baked into V's stored key order (Vp) at projection time.
//    => no LDS round-trip, no cross-lane ops in the inner loop.
//  - exp -> exp2 with log2(e) folded into Q's scale (saves a v_mul per exp).
//  - qkv/out GEMMs: 16x16-tile-per-wave (12288/4096 waves) for occupancy.

#define B_   2
#define S_   2048
#define D_   256
#define H_   8
#define DH_  32
#define NROW (B_*S_)      // 4096
#define KSPLIT 2
#define KKEYS (S_/KSPLIT) // 1024

typedef __attribute__((ext_vector_type(8))) short bf16x8;  // 8 bf16 (4 VGPRs)
typedef __attribute__((ext_vector_type(4))) float f32x4;

__device__ __forceinline__ f32x4 mfma_bf16(bf16x8 a, bf16x8 b, f32x4 c) {
    return __builtin_amdgcn_mfma_f32_16x16x32_bf16(a, b, c, 0, 0, 0);
}

__device__ __forceinline__ unsigned short f2bf_bits(float v) {
    __hip_bfloat16 h = __float2bfloat16(v);
    return *reinterpret_cast<unsigned short*>(&h);
}

// ---------------- split fp32 -> (hi, lo) bf16, all 5 tensors in one launch ----------------
__global__ void split_all(const float4* __restrict__ x,
                          const float4* __restrict__ wq, const float4* __restrict__ wk,
                          const float4* __restrict__ wv, const float4* __restrict__ wc,
                          ushort4* __restrict__ xh, ushort4* __restrict__ xl,
                          ushort4* __restrict__ wqh, ushort4* __restrict__ wql,
                          ushort4* __restrict__ wkh, ushort4* __restrict__ wkl,
                          ushort4* __restrict__ wvh, ushort4* __restrict__ wvl,
                          ushort4* __restrict__ wch, ushort4* __restrict__ wcl) {
    int i = blockIdx.x * 256 + threadIdx.x;   // total 327680 float4s
    const float4* src; ushort4 *ph, *pl; int off;
    if (i < 262144) { src = x; ph = xh; pl = xl; off = i; }
    else {
        int j = i - 262144;
        int rg = j >> 14; off = j & 16383;
        if (rg == 0)      { src = wq; ph = wqh; pl = wql; }
        else if (rg == 1) { src = wk; ph = wkh; pl = wkl; }
        else if (rg == 2) { src = wv; ph = wvh; pl = wvl; }
        else              { src = wc; ph = wch; pl = wcl; }
    }
    float4 v = src[off];
    float vv[4] = {v.x, v.y, v.z, v.w};
    ushort4 hb, lb;
    unsigned short* hp = (unsigned short*)&hb;
    unsigned short* lp = (unsigned short*)&lb;
    for (int c = 0; c < 4; c++) {
        __hip_bfloat16 h = __float2bfloat16(vv[c]);
        hp[c] = *reinterpret_cast<unsigned short*>(&h);
        lp[c] = f2bf_bits(vv[c] - __bfloat162float(h));
    }
    ph[off] = hb;
    pl[off] = lb;
}

// ---------------- QKV projection: y = x @ W^T + b ----------------
// grid (NROW/64=64, D/16=16, 3), block 256: wave w owns a 16x16 output tile.
// z=0 -> Q*(scale*log2e) [B,H,S,32], z=1 -> K [B,H,S,32],
// z=2 -> V transposed + key-slot-permuted: Vp[b,h,dh, kb*32 + slot].
__global__ __launch_bounds__(256) void qkv_gemm(
    const __hip_bfloat16* __restrict__ xh, const __hip_bfloat16* __restrict__ xl,
    const __hip_bfloat16* __restrict__ w0h, const __hip_bfloat16* __restrict__ w0l,
    const __hip_bfloat16* __restrict__ w1h, const __hip_bfloat16* __restrict__ w1l,
    const __hip_bfloat16* __restrict__ w2h, const __hip_bfloat16* __restrict__ w2l,
    const float* __restrict__ bq, const float* __restrict__ bk, const float* __restrict__ bvv,
    __hip_bfloat16* __restrict__ Q, __hip_bfloat16* __restrict__ K,
    __hip_bfloat16* __restrict__ Vp)
{
    int z = blockIdx.z;
    const __hip_bfloat16* wh = (z==0) ? w0h : (z==1) ? w1h : w2h;
    const __hip_bfloat16* wl = (z==0) ? w0l : (z==1) ? w1l : w2l;
    const float* bias = (z==0) ? bq : (z==1) ? bk : bvv;
    // Q gets 1/sqrt(32) * log2(e) folded in (softmax via exp2)
    const float sv = (z==0) ? 0.17677669529663687f * 1.4426950408889634f : 1.0f;

    int tid = threadIdx.x;
    int w = tid >> 6, lid = tid & 63, quad = lid >> 4, l15 = lid & 15;
    int row0 = (blockIdx.x * 4 + w) * 16;
    int col0 = blockIdx.y * 16;

    f32x4 acc = {};
#pragma unroll
    for (int k0 = 0; k0 < 256; k0 += 32) {
        int kk = k0 + quad * 8;
        size_t ro = (size_t)(row0 + l15) * 256 + kk;
        size_t co = (size_t)(col0 + l15) * 256 + kk;   // B[k][n] = W[n][k]
        bf16x8 ah = *(const bf16x8*)(xh + ro);
        bf16x8 al = *(const bf16x8*)(xl + ro);
        bf16x8 bh = *(const bf16x8*)(wh + co);
        bf16x8 bl = *(const bf16x8*)(wl + co);
        acc = mfma_bf16(ah, bh, acc);
        acc = mfma_bf16(ah, bl, acc);
        acc = mfma_bf16(al, bh, acc);
    }
    int col = col0 + l15;              // D-layout: col = lane&15
    int h = col >> 5, dh = col & 31;
    float bvl = bias[col];
    for (int r = 0; r < 4; r++) {
        int row = row0 + quad * 4 + r; // D-layout: row = quad*4+r
        int b = row >> 11, s = row & 2047;
        __hip_bfloat16 o = __float2bfloat16((acc[r] + bvl) * sv);
        if (z == 2) {
            int oo = s & 31;
            int slot = ((oo & 15) >> 2) * 8 + ((oo >> 4) << 2) + (oo & 3);
            Vp[(size_t)((b * H_ + h) * DH_ + dh) * S_ + (s & ~31) + slot] = o;
        } else {
            size_t idx = (size_t)((b * H_ + h) * S_ + s) * DH_ + dh;
            if (z == 0) Q[idx] = o; else K[idx] = o;
        }
    }
}

// ---------------- flash pass: partial l and O' per (b,h,q16,ksplit) ----------------
// grid (S/64=32, H=8, B*KSPLIT=4), block 256 = 4 waves, one q16-tile per wave.
// No LDS: S^T C-layout feeds PV directly as B-operand (slot-permuted V).
__global__ __launch_bounds__(256) void attn_flash(
    const __hip_bfloat16* __restrict__ Q, const __hip_bfloat16* __restrict__ K,
    const __hip_bfloat16* __restrict__ Vp,
    float* __restrict__ Opart, float* __restrict__ Lpart)
{
    int tid = threadIdx.x, w = tid >> 6, lid = tid & 63, quad = lid >> 4, l15 = lid & 15;
    int h = blockIdx.y;
    int b = blockIdx.z >> 1, ks = blockIdx.z & 1;
    int q0 = (blockIdx.x * 4 + w) * 16;
    const __hip_bfloat16* Qb = Q + (size_t)((b * H_ + h) * S_) * DH_;
    const __hip_bfloat16* Kb = K + (size_t)((b * H_ + h) * S_) * DH_;
    const __hip_bfloat16* Vb = Vp + (size_t)((b * H_ + h) * DH_) * S_;
    bf16x8 qf = *(const bf16x8*)(Qb + (size_t)(q0 + l15) * DH_ + quad * 8);  // B: n=q, k=dh
    f32x4 zacc = {};
    f32x4 oacc[2] = {};
    float lp0 = 0.f, lp1 = 0.f;

#pragma unroll 2
    for (int k0 = ks * KKEYS; k0 < (ks + 1) * KKEYS; k0 += 32) {
        // S^T = K.Q^T : A = K rows (m=key), B = Q^T (n=q)
        bf16x8 kf0 = *(const bf16x8*)(Kb + (size_t)(k0 + l15) * DH_ + quad * 8);
        bf16x8 kf1 = *(const bf16x8*)(Kb + (size_t)(k0 + 16 + l15) * DH_ + quad * 8);
        f32x4 c0 = mfma_bf16(kf0, qf, zacc);   // keys k0+quad*4+r, q=l15
        f32x4 c1 = mfma_bf16(kf1, qf, zacc);   // keys k0+16+quad*4+r
        float e0[4], e1[4];
        for (int r = 0; r < 4; r++) {
            e0[r] = exp2f(c0[r]);
            e1[r] = exp2f(c1[r]);
        }
        lp0 += e0[0] + e0[1] + e0[2] + e0[3];
        lp1 += e1[0] + e1[1] + e1[2] + e1[3];
        // P^T as B-operand: slots quad*8+j -> keys via pi (matches Vp layout)
        union { bf16x8 v; __hip_bfloat162 h2[4]; } pu;
        pu.h2[0] = __float22bfloat162_rn(make_float2(e0[0], e0[1]));
        pu.h2[1] = __float22bfloat162_rn(make_float2(e0[2], e0[3]));
        pu.h2[2] = __float22bfloat162_rn(make_float2(e1[0], e1[1]));
        pu.h2[3] = __float22bfloat162_rn(make_float2(e1[2], e1[3]));
        // O^T = V^T.P^T : A = Vp rows (m=d), slots already permuted in memory
        bf16x8 vf0 = *(const bf16x8*)(Vb + (size_t)(l15) * S_ + k0 + quad * 8);
        bf16x8 vf1 = *(const bf16x8*)(Vb + (size_t)(16 + l15) * S_ + k0 + quad * 8);
        oacc[0] = mfma_bf16(vf0, pu.v, oacc[0]);   // d 0..15
        oacc[1] = mfma_bf16(vf1, pu.v, oacc[1]);   // d 16..31
    }
    // l for q=l15: reduce across quads (each lane covered keys of its quad/reg)
    float lp = lp0 + lp1;
    lp += __shfl_xor(lp, 16);
    lp += __shfl_xor(lp, 32);

    size_t base = (size_t)((b * H_ + h) * KSPLIT + ks) * S_;
    if (lid < 16) Lpart[base + q0 + lid] = lp;
    // oacc[mt][r] = O^T[d=mt*16+quad*4+r][q=l15] -> two float4 stores
    f32x4* op = (f32x4*)(Opart + (base + q0 + l15) * DH_);
    op[quad] = oacc[0];
    op[quad + 4] = oacc[1];
}

// ---------------- combine: ctx = sum(O')/sum(l), invL ----------------
__global__ __launch_bounds__(256) void attn_combine(
    const float* __restrict__ Opart, const float* __restrict__ Lpart,
    __hip_bfloat16* __restrict__ cth, __hip_bfloat16* __restrict__ ctl,
    float* __restrict__ invL)
{
    int i = blockIdx.x * 256 + threadIdx.x;   // B*H*S*DH = 1,048,576
    int dh = i & 31;
    int s = (i >> 5) & (S_ - 1);
    int hb = i >> 16;                          // b*H+h in [0,16)
    float l = 0.f, o = 0.f;
    for (int ks = 0; ks < KSPLIT; ks++) {
        size_t base = (size_t)(hb * KSPLIT + ks) * S_ + s;
        l += Lpart[base];
        o += Opart[base * DH_ + dh];
    }
    float inv = 1.0f / l;
    float val = o * inv;
    int b = hb >> 3, h = hb & 7;
    size_t cidx = (size_t)(b * S_ + s) * D_ + h * DH_ + dh;
    __hip_bfloat16 hv = __float2bfloat16(val);
    cth[cidx] = hv;
    ctl[cidx] = __float2bfloat16(val - __bfloat162float(hv));
    if (dh == 0) invL[hb * S_ + s] = inv;
}

// ---------------- attn write: head-mean probs, 16q x 256k per block ----------------
// grid (S/256=8, S/16=128, B=2) = 2048 blocks; wave w owns cols k0+w*64..+64.
// Natural S orientation (q=rows) so stores stay coalesced along keys.
__global__ __launch_bounds__(256) void attn_write(
    const __hip_bfloat16* __restrict__ Q, const __hip_bfloat16* __restrict__ K,
    const float* __restrict__ invL, float* __restrict__ attn)
{
    __shared__ float invbuf[H_ * 16];
    int tid = threadIdx.x, w = tid >> 6, lid = tid & 63, quad = lid >> 4, l15 = lid & 15;
    int b = blockIdx.z;
    int q0 = blockIdx.y * 16;
    int k0 = blockIdx.x * 256 + w * 64;
    if (tid < 128) {
        int h = tid >> 4, r = tid & 15;
        invbuf[tid] = invL[(b * H_ + h) * S_ + q0 + r] * 0.125f;  // fold 1/H
    }
    __syncthreads();
    f32x4 zacc = {};
    float psum[4][4] = {};
    for (int h = 0; h < H_; h++) {
        const __hip_bfloat16* Qb = Q + (size_t)((b * H_ + h) * S_) * DH_;
        const __hip_bfloat16* Kb = K + (size_t)((b * H_ + h) * S_) * DH_;
        bf16x8 qf = *(const bf16x8*)(Qb + (size_t)(q0 + l15) * DH_ + quad * 8);
        float il[4];
        for (int r = 0; r < 4; r++) il[r] = invbuf[h * 16 + quad * 4 + r];
        for (int nt = 0; nt < 4; nt++) {
            bf16x8 kf = *(const bf16x8*)(Kb + (size_t)(k0 + nt * 16 + l15) * DH_ + quad * 8);
            f32x4 c = mfma_bf16(qf, kf, zacc);
            for (int r = 0; r < 4; r++)
                psum[nt][r] += exp2f(c[r]) * il[r];
        }
    }
    for (int nt = 0; nt < 4; nt++)
        for (int r = 0; r < 4; r++)
            attn[(size_t)(b * S_ + q0 + quad * 4 + r) * S_ + k0 + nt * 16 + l15] =
                psum[nt][r];
}

// ---------------- output projection: out = ctx @ wc^T + bc (fp32 out) ----------------
// grid (NROW/64=64, D/16=16), block 256: wave w owns a 16x16 output tile.
__global__ __launch_bounds__(256) void out_gemm(
    const __hip_bfloat16* __restrict__ ch, const __hip_bfloat16* __restrict__ cl,
    const __hip_bfloat16* __restrict__ wh, const __hip_bfloat16* __restrict__ wl,
    const float* __restrict__ bias, float* __restrict__ out)
{
    int tid = threadIdx.x;
    int w = tid >> 6, lid = tid & 63, quad = lid >> 4, l15 = lid & 15;
    int row0 = (blockIdx.x * 4 + w) * 16;
    int col0 = blockIdx.y * 16;

    f32x4 acc = {};
#pragma unroll
    for (int k0 = 0; k0 < 256; k0 += 32) {
        int kk = k0 + quad * 8;
        size_t ro = (size_t)(row0 + l15) * 256 + kk;
        size_t co = (size_t)(col0 + l15) * 256 + kk;
        bf16x8 ah = *(const bf16x8*)(ch + ro);
        bf16x8 al = *(const bf16x8*)(cl + ro);
        bf16x8 bh = *(const bf16x8*)(wh + co);
        bf16x8 bl = *(const bf16x8*)(wl + co);
        acc = mfma_bf16(ah, bh, acc);
        acc = mfma_bf16(ah, bl, acc);
        acc = mfma_bf16(al, bh, acc);
    }
    int col = col0 + l15;
    float bvl = bias[col];
    for (int r = 0; r < 4; r++) {
        int row = row0 + quad * 4 + r;
        out[(size_t)row * 256 + col] = acc[r] + bvl;
    }
}

extern "C" void kernel_launch(void* const* d_in, const int* in_sizes, int n_in,
                              void* d_out, int out_size, void* d_ws, size_t ws_size,
                              hipStream_t stream) {
    const float* x  = (const float*)d_in[0];
    const float* wq = (const float*)d_in[1];
    const float* bq = (const float*)d_in[2];
    const float* wk = (const float*)d_in[3];
    const float* bk = (const float*)d_in[4];
    const float* wv = (const float*)d_in[5];
    const float* bv = (const float*)d_in[6];
    const float* wc = (const float*)d_in[7];
    const float* bc = (const float*)d_in[8];

    char* ws = (char*)d_ws;
    const size_t MB = 1u << 20;
    const size_t KB128 = 128u * 1024u;
    __hip_bfloat16* xh  = (__hip_bfloat16*)(ws + 0 * MB);
    __hip_bfloat16* xl  = (__hip_bfloat16*)(ws + 2 * MB);
    __hip_bfloat16* wqh = (__hip_bfloat16*)(ws + 4 * MB + 0 * KB128);
    __hip_bfloat16* wql = (__hip_bfloat16*)(ws + 4 * MB + 1 * KB128);
    __hip_bfloat16* wkh = (__hip_bfloat16*)(ws + 4 * MB + 2 * KB128);
    __hip_bfloat16* wkl = (__hip_bfloat16*)(ws + 4 * MB + 3 * KB128);
    __hip_bfloat16* wvh = (__hip_bfloat16*)(ws + 4 * MB + 4 * KB128);
    __hip_bfloat16* wvl = (__hip_bfloat16*)(ws + 4 * MB + 5 * KB128);
    __hip_bfloat16* wch = (__hip_bfloat16*)(ws + 4 * MB + 6 * KB128);
    __hip_bfloat16* wcl = (__hip_bfloat16*)(ws + 4 * MB + 7 * KB128);
    __hip_bfloat16* Qb  = (__hip_bfloat16*)(ws + 5 * MB);
    __hip_bfloat16* Kb  = (__hip_bfloat16*)(ws + 7 * MB);
    __hip_bfloat16* Vpb = (__hip_bfloat16*)(ws + 9 * MB);
    __hip_bfloat16* cth = (__hip_bfloat16*)(ws + 11 * MB);
    __hip_bfloat16* ctl = (__hip_bfloat16*)(ws + 13 * MB);
    float* Opart = (float*)(ws + 15 * MB);                    // 8 MB
    float* Lpart = (float*)(ws + 23 * MB);                    // 256 KB
    float* invL  = (float*)(ws + 23 * MB + 256 * 1024);       // 128 KB

    float* outp  = (float*)d_out;
    float* attnp = outp + (size_t)NROW * D_;  // outputs concatenated: out, attention

    hipLaunchKernelGGL(split_all, dim3(1280), dim3(256), 0, stream,
                       (const float4*)x, (const float4*)wq, (const float4*)wk,
                       (const float4*)wv, (const float4*)wc,
                       (ushort4*)xh, (ushort4*)xl,
                       (ushort4*)wqh, (ushort4*)wql, (ushort4*)wkh, (ushort4*)wkl,
                       (ushort4*)wvh, (ushort4*)wvl, (ushort4*)wch, (ushort4*)wcl);

    hipLaunchKernelGGL(qkv_gemm, dim3(NROW / 64, D_ / 16, 3), dim3(256), 0, stream,
                       xh, xl, wqh, wql, wkh, wkl, wvh, wvl, bq, bk, bv, Qb, Kb, Vpb);

    hipLaunchKernelGGL(attn_flash, dim3(S_ / 64, H_, B_ * KSPLIT), dim3(256), 0, stream,
                       Qb, Kb, Vpb, Opart, Lpart);

    hipLaunchKernelGGL(attn_combine, dim3(4096), dim3(256), 0, stream,
                       Opart, Lpart, cth, ctl, invL);

    hipLaunchKernelGGL(attn_write, dim3(S_ / 256, S_ / 16, B_), dim3(256), 0, stream,
                       Qb, Kb, invL, attnp);

    hipLaunchKernelGGL(out_gemm, dim3(NROW / 64, D_ / 16), dim3(256), 0, stream,
                       cth, ctl, wch, wcl, bc, outp);
}

// Round 4
// 191.866 us; speedup vs baseline: 1.1346x; 1.1346x over previous
//
#include <hip/hip_runtime.h>
#include <hip/hip_bf16.h>

// MHA fwd: B=2, S=2048, D=256, H=8, Dh=32.
// Outputs: out [2,2048,256] fp32, attn_mean [2,2048,2048] fp32 (concat in d_out).
//
// R3: - qkv/out GEMMs back to 64x64-block / 2x2-frag-per-wave (R2's 16x16-per-wave
//       had zero fragment reuse -> +26us).  Vp slot permutation + exp2 fold kept.
//     - attn_flash: KSPLIT=4 -> 8192 waves (8/SIMD, VGPR<=64) to hide the
//       load->QK->exp->PV chain latency (R2 evidence: LDS removal was neutral,
//       occupancy was the binding constraint).

#define B_   2
#define S_   2048
#define D_   256
#define H_   8
#define DH_  32
#define NROW (B_*S_)      // 4096
#define KSPLIT 4
#define KKEYS (S_/KSPLIT) // 512

typedef __attribute__((ext_vector_type(8))) short bf16x8;  // 8 bf16 (4 VGPRs)
typedef __attribute__((ext_vector_type(4))) float f32x4;

__device__ __forceinline__ f32x4 mfma_bf16(bf16x8 a, bf16x8 b, f32x4 c) {
    return __builtin_amdgcn_mfma_f32_16x16x32_bf16(a, b, c, 0, 0, 0);
}

__device__ __forceinline__ unsigned short f2bf_bits(float v) {
    __hip_bfloat16 h = __float2bfloat16(v);
    return *reinterpret_cast<unsigned short*>(&h);
}

// ---------------- split fp32 -> (hi, lo) bf16, all 5 tensors in one launch ----------------
__global__ void split_all(const float4* __restrict__ x,
                          const float4* __restrict__ wq, const float4* __restrict__ wk,
                          const float4* __restrict__ wv, const float4* __restrict__ wc,
                          ushort4* __restrict__ xh, ushort4* __restrict__ xl,
                          ushort4* __restrict__ wqh, ushort4* __restrict__ wql,
                          ushort4* __restrict__ wkh, ushort4* __restrict__ wkl,
                          ushort4* __restrict__ wvh, ushort4* __restrict__ wvl,
                          ushort4* __restrict__ wch, ushort4* __restrict__ wcl) {
    int i = blockIdx.x * 256 + threadIdx.x;   // total 327680 float4s
    const float4* src; ushort4 *ph, *pl; int off;
    if (i < 262144) { src = x; ph = xh; pl = xl; off = i; }
    else {
        int j = i - 262144;
        int rg = j >> 14; off = j & 16383;
        if (rg == 0)      { src = wq; ph = wqh; pl = wql; }
        else if (rg == 1) { src = wk; ph = wkh; pl = wkl; }
        else if (rg == 2) { src = wv; ph = wvh; pl = wvl; }
        else              { src = wc; ph = wch; pl = wcl; }
    }
    float4 v = src[off];
    float vv[4] = {v.x, v.y, v.z, v.w};
    ushort4 hb, lb;
    unsigned short* hp = (unsigned short*)&hb;
    unsigned short* lp = (unsigned short*)&lb;
    for (int c = 0; c < 4; c++) {
        __hip_bfloat16 h = __float2bfloat16(vv[c]);
        hp[c] = *reinterpret_cast<unsigned short*>(&h);
        lp[c] = f2bf_bits(vv[c] - __bfloat162float(h));
    }
    ph[off] = hb;
    pl[off] = lb;
}

// ---------------- QKV projection: y = x @ W^T + b ----------------
// grid (NROW/64=64, 4, 3), block 256 (4 waves, 2x2 wave tiles of 32x32).
// z=0 -> Q*(scale*log2e) [B,H,S,32], z=1 -> K [B,H,S,32],
// z=2 -> V transposed + key-slot-permuted: Vp[b,h,dh, kb*32 + slot].
__global__ __launch_bounds__(256) void qkv_gemm(
    const __hip_bfloat16* __restrict__ xh, const __hip_bfloat16* __restrict__ xl,
    const __hip_bfloat16* __restrict__ w0h, const __hip_bfloat16* __restrict__ w0l,
    const __hip_bfloat16* __restrict__ w1h, const __hip_bfloat16* __restrict__ w1l,
    const __hip_bfloat16* __restrict__ w2h, const __hip_bfloat16* __restrict__ w2l,
    const float* __restrict__ bq, const float* __restrict__ bk, const float* __restrict__ bvv,
    __hip_bfloat16* __restrict__ Q, __hip_bfloat16* __restrict__ K,
    __hip_bfloat16* __restrict__ Vp)
{
    int z = blockIdx.z;
    const __hip_bfloat16* wh = (z==0) ? w0h : (z==1) ? w1h : w2h;
    const __hip_bfloat16* wl = (z==0) ? w0l : (z==1) ? w1l : w2l;
    const float* bias = (z==0) ? bq : (z==1) ? bk : bvv;
    // Q gets 1/sqrt(32) * log2(e) folded in (softmax via exp2)
    const float sv = (z==0) ? 0.17677669529663687f * 1.4426950408889634f : 1.0f;

    int tid = threadIdx.x;
    int w = tid >> 6, lid = tid & 63, quad = lid >> 4, l15 = lid & 15;
    int row0 = blockIdx.x * 64 + (w >> 1) * 32;
    int col0 = blockIdx.y * 64 + (w & 1) * 32;

    f32x4 acc[2][2] = {};
#pragma unroll
    for (int k0 = 0; k0 < 256; k0 += 32) {
        int kk = k0 + quad * 8;
        bf16x8 ah[2], al[2], bh[2], bl[2];
        for (int mi = 0; mi < 2; mi++) {
            size_t ro = (size_t)(row0 + mi * 16 + l15) * 256 + kk;
            ah[mi] = *(const bf16x8*)(xh + ro);
            al[mi] = *(const bf16x8*)(xl + ro);
        }
        for (int ni = 0; ni < 2; ni++) {
            size_t co = (size_t)(col0 + ni * 16 + l15) * 256 + kk;  // B[k][n] = W[n][k]
            bh[ni] = *(const bf16x8*)(wh + co);
            bl[ni] = *(const bf16x8*)(wl + co);
        }
        for (int mi = 0; mi < 2; mi++)
            for (int ni = 0; ni < 2; ni++) {
                acc[mi][ni] = mfma_bf16(ah[mi], bh[ni], acc[mi][ni]);
                acc[mi][ni] = mfma_bf16(ah[mi], bl[ni], acc[mi][ni]);
                acc[mi][ni] = mfma_bf16(al[mi], bh[ni], acc[mi][ni]);
            }
    }
    for (int mi = 0; mi < 2; mi++)
        for (int ni = 0; ni < 2; ni++) {
            int col = col0 + ni * 16 + l15;       // D-layout: col = lane&15
            int h = col >> 5, dh = col & 31;
            float bvl = bias[col];
            for (int r = 0; r < 4; r++) {
                int row = row0 + mi * 16 + quad * 4 + r;  // D-layout: row = quad*4+r
                int b = row >> 11, s = row & 2047;
                __hip_bfloat16 o = __float2bfloat16((acc[mi][ni][r] + bvl) * sv);
                if (z == 2) {
                    int oo = s & 31;
                    int slot = ((oo & 15) >> 2) * 8 + ((oo >> 4) << 2) + (oo & 3);
                    Vp[(size_t)((b * H_ + h) * DH_ + dh) * S_ + (s & ~31) + slot] = o;
                } else {
                    size_t idx = (size_t)((b * H_ + h) * S_ + s) * DH_ + dh;
                    if (z == 0) Q[idx] = o; else K[idx] = o;
                }
            }
        }
}

// ---------------- flash pass: partial l and O' per (b,h,q16,ksplit) ----------------
// grid (S/64=32, H=8, B*KSPLIT=8), block 256 = 4 waves, one q16-tile per wave.
// No LDS: S^T C-layout feeds PV directly as B-operand (slot-permuted V).
__global__ __launch_bounds__(256) void attn_flash(
    const __hip_bfloat16* __restrict__ Q, const __hip_bfloat16* __restrict__ K,
    const __hip_bfloat16* __restrict__ Vp,
    float* __restrict__ Opart, float* __restrict__ Lpart)
{
    int tid = threadIdx.x, w = tid >> 6, lid = tid & 63, quad = lid >> 4, l15 = lid & 15;
    int h = blockIdx.y;
    int b = blockIdx.z >> 2, ks = blockIdx.z & 3;
    int q0 = (blockIdx.x * 4 + w) * 16;
    const __hip_bfloat16* Qb = Q + (size_t)((b * H_ + h) * S_) * DH_;
    const __hip_bfloat16* Kb = K + (size_t)((b * H_ + h) * S_) * DH_;
    const __hip_bfloat16* Vb = Vp + (size_t)((b * H_ + h) * DH_) * S_;
    bf16x8 qf = *(const bf16x8*)(Qb + (size_t)(q0 + l15) * DH_ + quad * 8);  // B: n=q, k=dh
    f32x4 zacc = {};
    f32x4 oacc[2] = {};
    float lp0 = 0.f, lp1 = 0.f;

#pragma unroll 2
    for (int k0 = ks * KKEYS; k0 < (ks + 1) * KKEYS; k0 += 32) {
        // S^T = K.Q^T : A = K rows (m=key), B = Q^T (n=q)
        bf16x8 kf0 = *(const bf16x8*)(Kb + (size_t)(k0 + l15) * DH_ + quad * 8);
        bf16x8 kf1 = *(const bf16x8*)(Kb + (size_t)(k0 + 16 + l15) * DH_ + quad * 8);
        f32x4 c0 = mfma_bf16(kf0, qf, zacc);   // keys k0+quad*4+r, q=l15
        f32x4 c1 = mfma_bf16(kf1, qf, zacc);   // keys k0+16+quad*4+r
        float e0[4], e1[4];
        for (int r = 0; r < 4; r++) {
            e0[r] = exp2f(c0[r]);
            e1[r] = exp2f(c1[r]);
        }
        lp0 += e0[0] + e0[1] + e0[2] + e0[3];
        lp1 += e1[0] + e1[1] + e1[2] + e1[3];
        // P^T as B-operand: slots quad*8+j -> keys via pi (matches Vp layout)
        union { bf16x8 v; __hip_bfloat162 h2[4]; } pu;
        pu.h2[0] = __float22bfloat162_rn(make_float2(e0[0], e0[1]));
        pu.h2[1] = __float22bfloat162_rn(make_float2(e0[2], e0[3]));
        pu.h2[2] = __float22bfloat162_rn(make_float2(e1[0], e1[1]));
        pu.h2[3] = __float22bfloat162_rn(make_float2(e1[2], e1[3]));
        // O^T = V^T.P^T : A = Vp rows (m=d), slots already permuted in memory
        bf16x8 vf0 = *(const bf16x8*)(Vb + (size_t)(l15) * S_ + k0 + quad * 8);
        bf16x8 vf1 = *(const bf16x8*)(Vb + (size_t)(16 + l15) * S_ + k0 + quad * 8);
        oacc[0] = mfma_bf16(vf0, pu.v, oacc[0]);   // d 0..15
        oacc[1] = mfma_bf16(vf1, pu.v, oacc[1]);   // d 16..31
    }
    // l for q=l15: reduce across quads (each lane covered keys of its quad/reg)
    float lp = lp0 + lp1;
    lp += __shfl_xor(lp, 16);
    lp += __shfl_xor(lp, 32);

    size_t base = (size_t)((b * H_ + h) * KSPLIT + ks) * S_;
    if (lid < 16) Lpart[base + q0 + lid] = lp;
    // oacc[mt][r] = O^T[d=mt*16+quad*4+r][q=l15] -> two float4 stores
    f32x4* op = (f32x4*)(Opart + (base + q0 + l15) * DH_);
    op[quad] = oacc[0];
    op[quad + 4] = oacc[1];
}

// ---------------- combine: ctx = sum(O')/sum(l), invL ----------------
__global__ __launch_bounds__(256) void attn_combine(
    const float* __restrict__ Opart, const float* __restrict__ Lpart,
    __hip_bfloat16* __restrict__ cth, __hip_bfloat16* __restrict__ ctl,
    float* __restrict__ invL)
{
    int i = blockIdx.x * 256 + threadIdx.x;   // B*H*S*DH = 1,048,576
    int dh = i & 31;
    int s = (i >> 5) & (S_ - 1);
    int hb = i >> 16;                          // b*H+h in [0,16)
    float l = 0.f, o = 0.f;
#pragma unroll
    for (int ks = 0; ks < KSPLIT; ks++) {
        size_t base = (size_t)(hb * KSPLIT + ks) * S_ + s;
        l += Lpart[base];
        o += Opart[base * DH_ + dh];
    }
    float inv = 1.0f / l;
    float val = o * inv;
    int b = hb >> 3, h = hb & 7;
    size_t cidx = (size_t)(b * S_ + s) * D_ + h * DH_ + dh;
    __hip_bfloat16 hv = __float2bfloat16(val);
    cth[cidx] = hv;
    ctl[cidx] = __float2bfloat16(val - __bfloat162float(hv));
    if (dh == 0) invL[hb * S_ + s] = inv;
}

// ---------------- attn write: head-mean probs, 16q x 256k per block ----------------
// grid (S/256=8, S/16=128, B=2) = 2048 blocks; wave w owns cols k0+w*64..+64.
__global__ __launch_bounds__(256) void attn_write(
    const __hip_bfloat16* __restrict__ Q, const __hip_bfloat16* __restrict__ K,
    const float* __restrict__ invL, float* __restrict__ attn)
{
    __shared__ float invbuf[H_ * 16];
    int tid = threadIdx.x, w = tid >> 6, lid = tid & 63, quad = lid >> 4, l15 = lid & 15;
    int b = blockIdx.z;
    int q0 = blockIdx.y * 16;
    int k0 = blockIdx.x * 256 + w * 64;
    if (tid < 128) {
        int h = tid >> 4, r = tid & 15;
        invbuf[tid] = invL[(b * H_ + h) * S_ + q0 + r] * 0.125f;  // fold 1/H
    }
    __syncthreads();
    f32x4 zacc = {};
    float psum[4][4] = {};
    for (int h = 0; h < H_; h++) {
        const __hip_bfloat16* Qb = Q + (size_t)((b * H_ + h) * S_) * DH_;
        const __hip_bfloat16* Kb = K + (size_t)((b * H_ + h) * S_) * DH_;
        bf16x8 qf = *(const bf16x8*)(Qb + (size_t)(q0 + l15) * DH_ + quad * 8);
        float il[4];
        for (int r = 0; r < 4; r++) il[r] = invbuf[h * 16 + quad * 4 + r];
        for (int nt = 0; nt < 4; nt++) {
            bf16x8 kf = *(const bf16x8*)(Kb + (size_t)(k0 + nt * 16 + l15) * DH_ + quad * 8);
            f32x4 c = mfma_bf16(qf, kf, zacc);
            for (int r = 0; r < 4; r++)
                psum[nt][r] += exp2f(c[r]) * il[r];
        }
    }
    for (int nt = 0; nt < 4; nt++)
        for (int r = 0; r < 4; r++)
            attn[(size_t)(b * S_ + q0 + quad * 4 + r) * S_ + k0 + nt * 16 + l15] =
                psum[nt][r];
}

// ---------------- output projection: out = ctx @ wc^T + bc (fp32 out) ----------------
// grid (NROW/64=64, 4), block 256 (4 waves, 2x2 wave tiles of 32x32).
__global__ __launch_bounds__(256) void out_gemm(
    const __hip_bfloat16* __restrict__ ch, const __hip_bfloat16* __restrict__ cl,
    const __hip_bfloat16* __restrict__ wh, const __hip_bfloat16* __restrict__ wl,
    const float* __restrict__ bias, float* __restrict__ out)
{
    int tid = threadIdx.x;
    int w = tid >> 6, lid = tid & 63, quad = lid >> 4, l15 = lid & 15;
    int row0 = blockIdx.x * 64 + (w >> 1) * 32;
    int col0 = blockIdx.y * 64 + (w & 1) * 32;

    f32x4 acc[2][2] = {};
#pragma unroll
    for (int k0 = 0; k0 < 256; k0 += 32) {
        int kk = k0 + quad * 8;
        bf16x8 ah[2], al[2], bh[2], bl[2];
        for (int mi = 0; mi < 2; mi++) {
            size_t ro = (size_t)(row0 + mi * 16 + l15) * 256 + kk;
            ah[mi] = *(const bf16x8*)(ch + ro);
            al[mi] = *(const bf16x8*)(cl + ro);
        }
        for (int ni = 0; ni < 2; ni++) {
            size_t co = (size_t)(col0 + ni * 16 + l15) * 256 + kk;
            bh[ni] = *(const bf16x8*)(wh + co);
            bl[ni] = *(const bf16x8*)(wl + co);
        }
        for (int mi = 0; mi < 2; mi++)
            for (int ni = 0; ni < 2; ni++) {
                acc[mi][ni] = mfma_bf16(ah[mi], bh[ni], acc[mi][ni]);
                acc[mi][ni] = mfma_bf16(ah[mi], bl[ni], acc[mi][ni]);
                acc[mi][ni] = mfma_bf16(al[mi], bh[ni], acc[mi][ni]);
            }
    }
    for (int mi = 0; mi < 2; mi++)
        for (int ni = 0; ni < 2; ni++) {
            int col = col0 + ni * 16 + l15;
            float bvl = bias[col];
            for (int r = 0; r < 4; r++) {
                int row = row0 + mi * 16 + quad * 4 + r;
                out[(size_t)row * 256 + col] = acc[mi][ni][r] + bvl;
            }
        }
}

extern "C" void kernel_launch(void* const* d_in, const int* in_sizes, int n_in,
                              void* d_out, int out_size, void* d_ws, size_t ws_size,
                              hipStream_t stream) {
    const float* x  = (const float*)d_in[0];
    const float* wq = (const float*)d_in[1];
    const float* bq = (const float*)d_in[2];
    const float* wk = (const float*)d_in[3];
    const float* bk = (const float*)d_in[4];
    const float* wv = (const float*)d_in[5];
    const float* bv = (const float*)d_in[6];
    const float* wc = (const float*)d_in[7];
    const float* bc = (const float*)d_in[8];

    char* ws = (char*)d_ws;
    const size_t MB = 1u << 20;
    const size_t KB128 = 128u * 1024u;
    __hip_bfloat16* xh  = (__hip_bfloat16*)(ws + 0 * MB);
    __hip_bfloat16* xl  = (__hip_bfloat16*)(ws + 2 * MB);
    __hip_bfloat16* wqh = (__hip_bfloat16*)(ws + 4 * MB + 0 * KB128);
    __hip_bfloat16* wql = (__hip_bfloat16*)(ws + 4 * MB + 1 * KB128);
    __hip_bfloat16* wkh = (__hip_bfloat16*)(ws + 4 * MB + 2 * KB128);
    __hip_bfloat16* wkl = (__hip_bfloat16*)(ws + 4 * MB + 3 * KB128);
    __hip_bfloat16* wvh = (__hip_bfloat16*)(ws + 4 * MB + 4 * KB128);
    __hip_bfloat16* wvl = (__hip_bfloat16*)(ws + 4 * MB + 5 * KB128);
    __hip_bfloat16* wch = (__hip_bfloat16*)(ws + 4 * MB + 6 * KB128);
    __hip_bfloat16* wcl = (__hip_bfloat16*)(ws + 4 * MB + 7 * KB128);
    __hip_bfloat16* Qb  = (__hip_bfloat16*)(ws + 5 * MB);
    __hip_bfloat16* Kb  = (__hip_bfloat16*)(ws + 7 * MB);
    __hip_bfloat16* Vpb = (__hip_bfloat16*)(ws + 9 * MB);
    __hip_bfloat16* cth = (__hip_bfloat16*)(ws + 11 * MB);
    __hip_bfloat16* ctl = (__hip_bfloat16*)(ws + 13 * MB);
    float* Opart = (float*)(ws + 15 * MB);                    // 16 MB (KSPLIT=4)
    float* Lpart = (float*)(ws + 31 * MB);                    // 512 KB
    float* invL  = (float*)(ws + 31 * MB + 512 * 1024);       // 128 KB

    float* outp  = (float*)d_out;
    float* attnp = outp + (size_t)NROW * D_;  // outputs concatenated: out, attention

    hipLaunchKernelGGL(split_all, dim3(1280), dim3(256), 0, stream,
                       (const float4*)x, (const float4*)wq, (const float4*)wk,
                       (const float4*)wv, (const float4*)wc,
                       (ushort4*)xh, (ushort4*)xl,
                       (ushort4*)wqh, (ushort4*)wql, (ushort4*)wkh, (ushort4*)wkl,
                       (ushort4*)wvh, (ushort4*)wvl, (ushort4*)wch, (ushort4*)wcl);

    hipLaunchKernelGGL(qkv_gemm, dim3(NROW / 64, 4, 3), dim3(256), 0, stream,
                       xh, xl, wqh, wql, wkh, wkl, wvh, wvl, bq, bk, bv, Qb, Kb, Vpb);

    hipLaunchKernelGGL(attn_flash, dim3(S_ / 64, H_, B_ * KSPLIT), dim3(256), 0, stream,
                       Qb, Kb, Vpb, Opart, Lpart);

    hipLaunchKernelGGL(attn_combine, dim3(4096), dim3(256), 0, stream,
                       Opart, Lpart, cth, ctl, invL);

    hipLaunchKernelGGL(attn_write, dim3(S_ / 256, S_ / 16, B_), dim3(256), 0, stream,
                       Qb, Kb, invL, attnp);

    hipLaunchKernelGGL(out_gemm, dim3(NROW / 64, 4), dim3(256), 0, stream,
                       cth, ctl, wch, wcl, bc, outp);
}

// Round 5
// 163.757 us; speedup vs baseline: 1.3294x; 1.1717x over previous
//
#include <hip/hip_runtime.h>
#include <hip/hip_bf16.h>

// MHA fwd: B=2, S=2048, D=256, H=8, Dh=32.
// Outputs: out [2,2048,256] fp32, attn_mean [2,2048,2048] fp32 (concat in d_out).
//
// R4: fragment-linear Q/K/V layouts. R3 evidence: attn_flash pinned at 50us
// regardless of wave count -> loads were quarter-wave-uncoalesced (stride-64B
// within each 16-lane granule => ~16 transactions per load). Q/K/Vp are now
// stored in MFMA-fragment order so every fragment load is addr = base+lane*16B
// (fully coalesced). Math identical to R3.
//
// Fragment-linear layouts (per (b,h), 65536 elems = S*DH):
//  Q/K: block s0=s&~15: chunk16B[lane] = T[s0+(lane&15)][ (lane>>4)*8 ..+8 ]
//       idx = bh*65536 + (s>>4)*512 + (dh>>3)*128 + (s&15)*8 + (dh&7)
//  Vp:  block k0=s&~31, slot=pi(s&31) (PV B-operand slot permutation),
//       idx = bh*65536 + (s>>5)*1024 + (dh>>4)*512 + (slot>>3)*128 + (dh&15)*8 + (slot&7)

#define B_   2
#define S_   2048
#define D_   256
#define H_   8
#define DH_  32
#define NROW (B_*S_)      // 4096
#define KSPLIT 4
#define KKEYS (S_/KSPLIT) // 512

typedef __attribute__((ext_vector_type(8))) short bf16x8;  // 8 bf16 (4 VGPRs)
typedef __attribute__((ext_vector_type(4))) float f32x4;

__device__ __forceinline__ f32x4 mfma_bf16(bf16x8 a, bf16x8 b, f32x4 c) {
    return __builtin_amdgcn_mfma_f32_16x16x32_bf16(a, b, c, 0, 0, 0);
}

__device__ __forceinline__ unsigned short f2bf_bits(float v) {
    __hip_bfloat16 h = __float2bfloat16(v);
    return *reinterpret_cast<unsigned short*>(&h);
}

// ---------------- split fp32 -> (hi, lo) bf16, all 5 tensors in one launch ----------------
__global__ void split_all(const float4* __restrict__ x,
                          const float4* __restrict__ wq, const float4* __restrict__ wk,
                          const float4* __restrict__ wv, const float4* __restrict__ wc,
                          ushort4* __restrict__ xh, ushort4* __restrict__ xl,
                          ushort4* __restrict__ wqh, ushort4* __restrict__ wql,
                          ushort4* __restrict__ wkh, ushort4* __restrict__ wkl,
                          ushort4* __restrict__ wvh, ushort4* __restrict__ wvl,
                          ushort4* __restrict__ wch, ushort4* __restrict__ wcl) {
    int i = blockIdx.x * 256 + threadIdx.x;   // total 327680 float4s
    const float4* src; ushort4 *ph, *pl; int off;
    if (i < 262144) { src = x; ph = xh; pl = xl; off = i; }
    else {
        int j = i - 262144;
        int rg = j >> 14; off = j & 16383;
        if (rg == 0)      { src = wq; ph = wqh; pl = wql; }
        else if (rg == 1) { src = wk; ph = wkh; pl = wkl; }
        else if (rg == 2) { src = wv; ph = wvh; pl = wvl; }
        else              { src = wc; ph = wch; pl = wcl; }
    }
    float4 v = src[off];
    float vv[4] = {v.x, v.y, v.z, v.w};
    ushort4 hb, lb;
    unsigned short* hp = (unsigned short*)&hb;
    unsigned short* lp = (unsigned short*)&lb;
    for (int c = 0; c < 4; c++) {
        __hip_bfloat16 h = __float2bfloat16(vv[c]);
        hp[c] = *reinterpret_cast<unsigned short*>(&h);
        lp[c] = f2bf_bits(vv[c] - __bfloat162float(h));
    }
    ph[off] = hb;
    pl[off] = lb;
}

// ---------------- QKV projection: y = x @ W^T + b ----------------
// grid (NROW/64=64, 4, 3), block 256 (4 waves, 2x2 wave tiles of 32x32).
// Outputs in fragment-linear layout (see header). Q gets scale*log2e folded in.
__global__ __launch_bounds__(256) void qkv_gemm(
    const __hip_bfloat16* __restrict__ xh, const __hip_bfloat16* __restrict__ xl,
    const __hip_bfloat16* __restrict__ w0h, const __hip_bfloat16* __restrict__ w0l,
    const __hip_bfloat16* __restrict__ w1h, const __hip_bfloat16* __restrict__ w1l,
    const __hip_bfloat16* __restrict__ w2h, const __hip_bfloat16* __restrict__ w2l,
    const float* __restrict__ bq, const float* __restrict__ bk, const float* __restrict__ bvv,
    __hip_bfloat16* __restrict__ Qf, __hip_bfloat16* __restrict__ Kf,
    __hip_bfloat16* __restrict__ Vf)
{
    int z = blockIdx.z;
    const __hip_bfloat16* wh = (z==0) ? w0h : (z==1) ? w1h : w2h;
    const __hip_bfloat16* wl = (z==0) ? w0l : (z==1) ? w1l : w2l;
    const float* bias = (z==0) ? bq : (z==1) ? bk : bvv;
    const float sv = (z==0) ? 0.17677669529663687f * 1.4426950408889634f : 1.0f;

    int tid = threadIdx.x;
    int w = tid >> 6, lid = tid & 63, quad = lid >> 4, l15 = lid & 15;
    int row0 = blockIdx.x * 64 + (w >> 1) * 32;
    int col0 = blockIdx.y * 64 + (w & 1) * 32;

    f32x4 acc[2][2] = {};
#pragma unroll
    for (int k0 = 0; k0 < 256; k0 += 32) {
        int kk = k0 + quad * 8;
        bf16x8 ah[2], al[2], bh[2], bl[2];
        for (int mi = 0; mi < 2; mi++) {
            size_t ro = (size_t)(row0 + mi * 16 + l15) * 256 + kk;
            ah[mi] = *(const bf16x8*)(xh + ro);
            al[mi] = *(const bf16x8*)(xl + ro);
        }
        for (int ni = 0; ni < 2; ni++) {
            size_t co = (size_t)(col0 + ni * 16 + l15) * 256 + kk;  // B[k][n] = W[n][k]
            bh[ni] = *(const bf16x8*)(wh + co);
            bl[ni] = *(const bf16x8*)(wl + co);
        }
        for (int mi = 0; mi < 2; mi++)
            for (int ni = 0; ni < 2; ni++) {
                acc[mi][ni] = mfma_bf16(ah[mi], bh[ni], acc[mi][ni]);
                acc[mi][ni] = mfma_bf16(ah[mi], bl[ni], acc[mi][ni]);
                acc[mi][ni] = mfma_bf16(al[mi], bh[ni], acc[mi][ni]);
            }
    }
    for (int mi = 0; mi < 2; mi++)
        for (int ni = 0; ni < 2; ni++) {
            int col = col0 + ni * 16 + l15;       // D-layout: col = lane&15
            int h = col >> 5, dh = col & 31;
            float bvl = bias[col];
            for (int r = 0; r < 4; r++) {
                int row = row0 + mi * 16 + quad * 4 + r;  // D-layout: row = quad*4+r
                int b = row >> 11, s = row & 2047;
                __hip_bfloat16 o = __float2bfloat16((acc[mi][ni][r] + bvl) * sv);
                size_t bh_base = (size_t)(b * H_ + h) * (S_ * DH_);
                if (z == 2) {
                    int oo = s & 31;
                    int slot = ((oo & 15) >> 2) * 8 + ((oo >> 4) << 2) + (oo & 3);
                    Vf[bh_base + (s >> 5) * 1024 + (dh >> 4) * 512
                       + (slot >> 3) * 128 + (dh & 15) * 8 + (slot & 7)] = o;
                } else {
                    size_t idx = bh_base + (s >> 4) * 512 + (dh >> 3) * 128
                                 + (s & 15) * 8 + (dh & 7);
                    if (z == 0) Qf[idx] = o; else Kf[idx] = o;
                }
            }
        }
}

// ---------------- flash pass: partial l and O' per (b,h,q16,ksplit) ----------------
// grid (S/64=32, H=8, B*KSPLIT=8), block 256 = 4 waves, one q16-tile per wave.
// All fragment loads are lane-linear (base + lid*16B), fully coalesced.
__global__ __launch_bounds__(256) void attn_flash(
    const __hip_bfloat16* __restrict__ Qf, const __hip_bfloat16* __restrict__ Kf,
    const __hip_bfloat16* __restrict__ Vf,
    float* __restrict__ Opart, float* __restrict__ Lpart)
{
    int tid = threadIdx.x, w = tid >> 6, lid = tid & 63, quad = lid >> 4, l15 = lid & 15;
    int h = blockIdx.y;
    int b = blockIdx.z >> 2, ks = blockIdx.z & 3;
    int q0 = (blockIdx.x * 4 + w) * 16;
    size_t bh_base = (size_t)(b * H_ + h) * (S_ * DH_);
    const __hip_bfloat16* Qp = Qf + bh_base + (q0 >> 4) * 512 + lid * 8;
    const __hip_bfloat16* Kp = Kf + bh_base + lid * 8;
    const __hip_bfloat16* Vp = Vf + bh_base + lid * 8;
    bf16x8 qf = *(const bf16x8*)Qp;                 // B: n=q (lane&15), k=dh
    f32x4 zacc = {};
    f32x4 oacc[2] = {};
    float lp0 = 0.f, lp1 = 0.f;

#pragma unroll 2
    for (int k0 = ks * KKEYS; k0 < (ks + 1) * KKEYS; k0 += 32) {
        // S^T = K.Q^T : A = K rows (m=key), B = Q^T (n=q)
        bf16x8 kf0 = *(const bf16x8*)(Kp + (k0 >> 4) * 512);
        bf16x8 kf1 = *(const bf16x8*)(Kp + (k0 >> 4) * 512 + 512);
        f32x4 c0 = mfma_bf16(kf0, qf, zacc);   // keys k0+quad*4+r, q=l15
        f32x4 c1 = mfma_bf16(kf1, qf, zacc);   // keys k0+16+quad*4+r
        float e0[4], e1[4];
        for (int r = 0; r < 4; r++) {
            e0[r] = exp2f(c0[r]);
            e1[r] = exp2f(c1[r]);
        }
        lp0 += e0[0] + e0[1] + e0[2] + e0[3];
        lp1 += e1[0] + e1[1] + e1[2] + e1[3];
        // P^T as B-operand: slots quad*8+j -> keys via pi (baked into Vf layout)
        union { bf16x8 v; __hip_bfloat162 h2[4]; } pu;
        pu.h2[0] = __float22bfloat162_rn(make_float2(e0[0], e0[1]));
        pu.h2[1] = __float22bfloat162_rn(make_float2(e0[2], e0[3]));
        pu.h2[2] = __float22bfloat162_rn(make_float2(e1[0], e1[1]));
        pu.h2[3] = __float22bfloat162_rn(make_float2(e1[2], e1[3]));
        // O^T = V^T.P^T : A = Vf rows (m=d)
        bf16x8 vf0 = *(const bf16x8*)(Vp + (k0 >> 5) * 1024);
        bf16x8 vf1 = *(const bf16x8*)(Vp + (k0 >> 5) * 1024 + 512);
        oacc[0] = mfma_bf16(vf0, pu.v, oacc[0]);   // d 0..15
        oacc[1] = mfma_bf16(vf1, pu.v, oacc[1]);   // d 16..31
    }
    // l for q=l15: reduce across quads (each lane covered keys of its quad/reg)
    float lp = lp0 + lp1;
    lp += __shfl_xor(lp, 16);
    lp += __shfl_xor(lp, 32);

    size_t base = (size_t)((b * H_ + h) * KSPLIT + ks) * S_;
    if (lid < 16) Lpart[base + q0 + lid] = lp;
    // oacc[mt][r] = O^T[d=mt*16+quad*4+r][q=l15] -> two float4 stores
    f32x4* op = (f32x4*)(Opart + (base + q0 + l15) * DH_);
    op[quad] = oacc[0];
    op[quad + 4] = oacc[1];
}

// ---------------- combine: ctx = sum(O')/sum(l), invL ----------------
__global__ __launch_bounds__(256) void attn_combine(
    const float* __restrict__ Opart, const float* __restrict__ Lpart,
    __hip_bfloat16* __restrict__ cth, __hip_bfloat16* __restrict__ ctl,
    float* __restrict__ invL)
{
    int i = blockIdx.x * 256 + threadIdx.x;   // B*H*S*DH = 1,048,576
    int dh = i & 31;
    int s = (i >> 5) & (S_ - 1);
    int hb = i >> 16;                          // b*H+h in [0,16)
    float l = 0.f, o = 0.f;
#pragma unroll
    for (int ks = 0; ks < KSPLIT; ks++) {
        size_t base = (size_t)(hb * KSPLIT + ks) * S_ + s;
        l += Lpart[base];
        o += Opart[base * DH_ + dh];
    }
    float inv = 1.0f / l;
    float val = o * inv;
    int b = hb >> 3, h = hb & 7;
    size_t cidx = (size_t)(b * S_ + s) * D_ + h * DH_ + dh;
    __hip_bfloat16 hv = __float2bfloat16(val);
    cth[cidx] = hv;
    ctl[cidx] = __float2bfloat16(val - __bfloat162float(hv));
    if (dh == 0) invL[hb * S_ + s] = inv;
}

// ---------------- attn write: head-mean probs, 16q x 256k per block ----------------
// grid (S/256=8, S/16=128, B=2) = 2048 blocks; wave w owns cols k0+w*64..+64.
__global__ __launch_bounds__(256) void attn_write(
    const __hip_bfloat16* __restrict__ Qf, const __hip_bfloat16* __restrict__ Kf,
    const float* __restrict__ invL, float* __restrict__ attn)
{
    __shared__ float invbuf[H_ * 16];
    int tid = threadIdx.x, w = tid >> 6, lid = tid & 63, quad = lid >> 4, l15 = lid & 15;
    int b = blockIdx.z;
    int q0 = blockIdx.y * 16;
    int k0 = blockIdx.x * 256 + w * 64;
    if (tid < 128) {
        int h = tid >> 4, r = tid & 15;
        invbuf[tid] = invL[(b * H_ + h) * S_ + q0 + r] * 0.125f;  // fold 1/H
    }
    __syncthreads();
    f32x4 zacc = {};
    float psum[4][4] = {};
    for (int h = 0; h < H_; h++) {
        size_t bh_base = (size_t)(b * H_ + h) * (S_ * DH_);
        bf16x8 qf = *(const bf16x8*)(Qf + bh_base + (q0 >> 4) * 512 + lid * 8);
        const __hip_bfloat16* Kp = Kf + bh_base + (k0 >> 4) * 512 + lid * 8;
        float il[4];
        for (int r = 0; r < 4; r++) il[r] = invbuf[h * 16 + quad * 4 + r];
        for (int nt = 0; nt < 4; nt++) {
            bf16x8 kf = *(const bf16x8*)(Kp + nt * 512);
            f32x4 c = mfma_bf16(qf, kf, zacc);   // S: row=q (quad*4+r), col=key (l15)... no:
            // A=Q (m=q=lane&15 -> col), ... C-layout: col=lane&15 -> here col=q? No:
            // mfma(qf, kf): A=Q rows m=q0+l15, B=K^T cols n=key. C: col(lane&15)=n=key,
            // row(quad*4+r)=m=q. Wait—C col = lane&15 indexes... (same as R1-R3, unchanged)
            for (int r = 0; r < 4; r++)
                psum[nt][r] += exp2f(c[r]) * il[r];
        }
    }
    for (int nt = 0; nt < 4; nt++)
        for (int r = 0; r < 4; r++)
            attn[(size_t)(b * S_ + q0 + quad * 4 + r) * S_ + k0 + nt * 16 + l15] =
                psum[nt][r];
}

// ---------------- output projection: out = ctx @ wc^T + bc (fp32 out) ----------------
// grid (NROW/64=64, 4), block 256 (4 waves, 2x2 wave tiles of 32x32).
__global__ __launch_bounds__(256) void out_gemm(
    const __hip_bfloat16* __restrict__ ch, const __hip_bfloat16* __restrict__ cl,
    const __hip_bfloat16* __restrict__ wh, const __hip_bfloat16* __restrict__ wl,
    const float* __restrict__ bias, float* __restrict__ out)
{
    int tid = threadIdx.x;
    int w = tid >> 6, lid = tid & 63, quad = lid >> 4, l15 = lid & 15;
    int row0 = blockIdx.x * 64 + (w >> 1) * 32;
    int col0 = blockIdx.y * 64 + (w & 1) * 32;

    f32x4 acc[2][2] = {};
#pragma unroll
    for (int k0 = 0; k0 < 256; k0 += 32) {
        int kk = k0 + quad * 8;
        bf16x8 ah[2], al[2], bh[2], bl[2];
        for (int mi = 0; mi < 2; mi++) {
            size_t ro = (size_t)(row0 + mi * 16 + l15) * 256 + kk;
            ah[mi] = *(const bf16x8*)(ch + ro);
            al[mi] = *(const bf16x8*)(cl + ro);
        }
        for (int ni = 0; ni < 2; ni++) {
            size_t co = (size_t)(col0 + ni * 16 + l15) * 256 + kk;
            bh[ni] = *(const bf16x8*)(wh + co);
            bl[ni] = *(const bf16x8*)(wl + co);
        }
        for (int mi = 0; mi < 2; mi++)
            for (int ni = 0; ni < 2; ni++) {
                acc[mi][ni] = mfma_bf16(ah[mi], bh[ni], acc[mi][ni]);
                acc[mi][ni] = mfma_bf16(ah[mi], bl[ni], acc[mi][ni]);
                acc[mi][ni] = mfma_bf16(al[mi], bh[ni], acc[mi][ni]);
            }
    }
    for (int mi = 0; mi < 2; mi++)
        for (int ni = 0; ni < 2; ni++) {
            int col = col0 + ni * 16 + l15;
            float bvl = bias[col];
            for (int r = 0; r < 4; r++) {
                int row = row0 + mi * 16 + quad * 4 + r;
                out[(size_t)row * 256 + col] = acc[mi][ni][r] + bvl;
            }
        }
}

extern "C" void kernel_launch(void* const* d_in, const int* in_sizes, int n_in,
                              void* d_out, int out_size, void* d_ws, size_t ws_size,
                              hipStream_t stream) {
    const float* x  = (const float*)d_in[0];
    const float* wq = (const float*)d_in[1];
    const float* bq = (const float*)d_in[2];
    const float* wk = (const float*)d_in[3];
    const float* bk = (const float*)d_in[4];
    const float* wv = (const float*)d_in[5];
    const float* bv = (const float*)d_in[6];
    const float* wc = (const float*)d_in[7];
    const float* bc = (const float*)d_in[8];

    char* ws = (char*)d_ws;
    const size_t MB = 1u << 20;
    const size_t KB128 = 128u * 1024u;
    __hip_bfloat16* xh  = (__hip_bfloat16*)(ws + 0 * MB);
    __hip_bfloat16* xl  = (__hip_bfloat16*)(ws + 2 * MB);
    __hip_bfloat16* wqh = (__hip_bfloat16*)(ws + 4 * MB + 0 * KB128);
    __hip_bfloat16* wql = (__hip_bfloat16*)(ws + 4 * MB + 1 * KB128);
    __hip_bfloat16* wkh = (__hip_bfloat16*)(ws + 4 * MB + 2 * KB128);
    __hip_bfloat16* wkl = (__hip_bfloat16*)(ws + 4 * MB + 3 * KB128);
    __hip_bfloat16* wvh = (__hip_bfloat16*)(ws + 4 * MB + 4 * KB128);
    __hip_bfloat16* wvl = (__hip_bfloat16*)(ws + 4 * MB + 5 * KB128);
    __hip_bfloat16* wch = (__hip_bfloat16*)(ws + 4 * MB + 6 * KB128);
    __hip_bfloat16* wcl = (__hip_bfloat16*)(ws + 4 * MB + 7 * KB128);
    __hip_bfloat16* Qfb = (__hip_bfloat16*)(ws + 5 * MB);
    __hip_bfloat16* Kfb = (__hip_bfloat16*)(ws + 7 * MB);
    __hip_bfloat16* Vfb = (__hip_bfloat16*)(ws + 9 * MB);
    __hip_bfloat16* cth = (__hip_bfloat16*)(ws + 11 * MB);
    __hip_bfloat16* ctl = (__hip_bfloat16*)(ws + 13 * MB);
    float* Opart = (float*)(ws + 15 * MB);                    // 16 MB (KSPLIT=4)
    float* Lpart = (float*)(ws + 31 * MB);                    // 512 KB
    float* invL  = (float*)(ws + 31 * MB + 512 * 1024);       // 128 KB

    float* outp  = (float*)d_out;
    float* attnp = outp + (size_t)NROW * D_;  // outputs concatenated: out, attention

    hipLaunchKernelGGL(split_all, dim3(1280), dim3(256), 0, stream,
                       (const float4*)x, (const float4*)wq, (const float4*)wk,
                       (const float4*)wv, (const float4*)wc,
                       (ushort4*)xh, (ushort4*)xl,
                       (ushort4*)wqh, (ushort4*)wql, (ushort4*)wkh, (ushort4*)wkl,
                       (ushort4*)wvh, (ushort4*)wvl, (ushort4*)wch, (ushort4*)wcl);

    hipLaunchKernelGGL(qkv_gemm, dim3(NROW / 64, 4, 3), dim3(256), 0, stream,
                       xh, xl, wqh, wql, wkh, wkl, wvh, wvl, bq, bk, bv, Qfb, Kfb, Vfb);

    hipLaunchKernelGGL(attn_flash, dim3(S_ / 64, H_, B_ * KSPLIT), dim3(256), 0, stream,
                       Qfb, Kfb, Vfb, Opart, Lpart);

    hipLaunchKernelGGL(attn_combine, dim3(4096), dim3(256), 0, stream,
                       Opart, Lpart, cth, ctl, invL);

    hipLaunchKernelGGL(attn_write, dim3(S_ / 256, S_ / 16, B_), dim3(256), 0, stream,
                       Qfb, Kfb, invL, attnp);

    hipLaunchKernelGGL(out_gemm, dim3(NROW / 64, 4), dim3(256), 0, stream,
                       cth, ctl, wch, wcl, bc, outp);
}

// Round 6
// 146.530 us; speedup vs baseline: 1.4857x; 1.1176x over previous
//
#include <hip/hip_runtime.h>
#include <hip/hip_bf16.h>

// MHA fwd: B=2, S=2048, D=256, H=8, Dh=32.
// Outputs: out [2,2048,256] fp32, attn_mean [2,2048,2048] fp32 (concat in d_out).
//
// R5: fragment-linear GEMM operand layouts. R0-R4 evidence: qkv/out GEMM
// fragment loads from row-major arrays stride 512B per lane within each
// 16-lane coalescing granule (same disease R4 fixed in attention). All split
// outputs (xh/xl, w*h/w*l) and ctx (cth/ctl) are now stored in MFMA-fragment
// order: fragidx(m,k) = (m>>4)*4096 + (k>>5)*512 + ((k>>3)&3)*128 + (m&15)*8 + (k&7)
// so every GEMM fragment load is base + lane*16B. Math identical to R4.

#define B_   2
#define S_   2048
#define D_   256
#define H_   8
#define DH_  32
#define NROW (B_*S_)      // 4096
#define KSPLIT 4
#define KKEYS (S_/KSPLIT) // 512

typedef __attribute__((ext_vector_type(8))) short bf16x8;  // 8 bf16 (4 VGPRs)
typedef __attribute__((ext_vector_type(4))) float f32x4;

__device__ __forceinline__ f32x4 mfma_bf16(bf16x8 a, bf16x8 b, f32x4 c) {
    return __builtin_amdgcn_mfma_f32_16x16x32_bf16(a, b, c, 0, 0, 0);
}

__device__ __forceinline__ unsigned short f2bf_bits(float v) {
    __hip_bfloat16 h = __float2bfloat16(v);
    return *reinterpret_cast<unsigned short*>(&h);
}

// fragment-linear index for a row-major [R x 256] matrix element (m, k)
__device__ __forceinline__ size_t fragidx(int m, int k) {
    return (size_t)(m >> 4) * 4096 + (k >> 5) * 512 + ((k >> 3) & 3) * 128
           + (m & 15) * 8 + (k & 7);
}

// ---------------- split fp32 -> (hi, lo) bf16, fragment-linear, one launch ----------------
// thread i handles 4 consecutive row-major elements (m = off>>6, k = (off&63)*4);
// those 4 land contiguous + 8B-aligned in the fragment layout.
__global__ void split_all(const float4* __restrict__ x,
                          const float4* __restrict__ wq, const float4* __restrict__ wk,
                          const float4* __restrict__ wv, const float4* __restrict__ wc,
                          ushort4* __restrict__ xh, ushort4* __restrict__ xl,
                          ushort4* __restrict__ wqh, ushort4* __restrict__ wql,
                          ushort4* __restrict__ wkh, ushort4* __restrict__ wkl,
                          ushort4* __restrict__ wvh, ushort4* __restrict__ wvl,
                          ushort4* __restrict__ wch, ushort4* __restrict__ wcl) {
    int i = blockIdx.x * 256 + threadIdx.x;   // total 327680 float4s
    const float4* src; ushort4 *ph, *pl; int off;
    if (i < 262144) { src = x; ph = xh; pl = xl; off = i; }
    else {
        int j = i - 262144;
        int rg = j >> 14; off = j & 16383;
        if (rg == 0)      { src = wq; ph = wqh; pl = wql; }
        else if (rg == 1) { src = wk; ph = wkh; pl = wkl; }
        else if (rg == 2) { src = wv; ph = wvh; pl = wvl; }
        else              { src = wc; ph = wch; pl = wcl; }
    }
    float4 v = src[off];
    float vv[4] = {v.x, v.y, v.z, v.w};
    ushort4 hb, lb;
    unsigned short* hp = (unsigned short*)&hb;
    unsigned short* lp = (unsigned short*)&lb;
    for (int c = 0; c < 4; c++) {
        __hip_bfloat16 h = __float2bfloat16(vv[c]);
        hp[c] = *reinterpret_cast<unsigned short*>(&h);
        lp[c] = f2bf_bits(vv[c] - __bfloat162float(h));
    }
    int m = off >> 6, k = (off & 63) * 4;
    size_t fi = fragidx(m, k);          // divisible by 4
    ph[fi >> 2] = hb;
    pl[fi >> 2] = lb;
}

// ---------------- QKV projection: y = x @ W^T + b ----------------
// grid (NROW/64=64, 4, 3), block 256 (4 waves, 2x2 wave tiles of 32x32).
// All A/B fragment loads are lane-linear now. Outputs fragment-linear Q/K/Vp
// layouts for attention (unchanged from R4). Q gets scale*log2e folded in.
__global__ __launch_bounds__(256) void qkv_gemm(
    const __hip_bfloat16* __restrict__ xh, const __hip_bfloat16* __restrict__ xl,
    const __hip_bfloat16* __restrict__ w0h, const __hip_bfloat16* __restrict__ w0l,
    const __hip_bfloat16* __restrict__ w1h, const __hip_bfloat16* __restrict__ w1l,
    const __hip_bfloat16* __restrict__ w2h, const __hip_bfloat16* __restrict__ w2l,
    const float* __restrict__ bq, const float* __restrict__ bk, const float* __restrict__ bvv,
    __hip_bfloat16* __restrict__ Qf, __hip_bfloat16* __restrict__ Kf,
    __hip_bfloat16* __restrict__ Vf)
{
    int z = blockIdx.z;
    const __hip_bfloat16* wh = (z==0) ? w0h : (z==1) ? w1h : w2h;
    const __hip_bfloat16* wl = (z==0) ? w0l : (z==1) ? w1l : w2l;
    const float* bias = (z==0) ? bq : (z==1) ? bk : bvv;
    const float sv = (z==0) ? 0.17677669529663687f * 1.4426950408889634f : 1.0f;

    int tid = threadIdx.x;
    int w = tid >> 6, lid = tid & 63, quad = lid >> 4, l15 = lid & 15;
    int row0 = blockIdx.x * 64 + (w >> 1) * 32;
    int col0 = blockIdx.y * 64 + (w & 1) * 32;

    f32x4 acc[2][2] = {};
#pragma unroll
    for (int k0 = 0; k0 < 256; k0 += 32) {
        bf16x8 ah[2], al[2], bh[2], bl[2];
        for (int mi = 0; mi < 2; mi++) {
            size_t ro = (size_t)((row0 + mi * 16) >> 4) * 4096 + (k0 >> 5) * 512 + lid * 8;
            ah[mi] = *(const bf16x8*)(xh + ro);
            al[mi] = *(const bf16x8*)(xl + ro);
        }
        for (int ni = 0; ni < 2; ni++) {
            size_t co = (size_t)((col0 + ni * 16) >> 4) * 4096 + (k0 >> 5) * 512 + lid * 8;
            bh[ni] = *(const bf16x8*)(wh + co);
            bl[ni] = *(const bf16x8*)(wl + co);
        }
        for (int mi = 0; mi < 2; mi++)
            for (int ni = 0; ni < 2; ni++) {
                acc[mi][ni] = mfma_bf16(ah[mi], bh[ni], acc[mi][ni]);
                acc[mi][ni] = mfma_bf16(ah[mi], bl[ni], acc[mi][ni]);
                acc[mi][ni] = mfma_bf16(al[mi], bh[ni], acc[mi][ni]);
            }
    }
    for (int mi = 0; mi < 2; mi++)
        for (int ni = 0; ni < 2; ni++) {
            int col = col0 + ni * 16 + l15;       // D-layout: col = lane&15
            int h = col >> 5, dh = col & 31;
            float bvl = bias[col];
            for (int r = 0; r < 4; r++) {
                int row = row0 + mi * 16 + quad * 4 + r;  // D-layout: row = quad*4+r
                int b = row >> 11, s = row & 2047;
                __hip_bfloat16 o = __float2bfloat16((acc[mi][ni][r] + bvl) * sv);
                size_t bh_base = (size_t)(b * H_ + h) * (S_ * DH_);
                if (z == 2) {
                    int oo = s & 31;
                    int slot = ((oo & 15) >> 2) * 8 + ((oo >> 4) << 2) + (oo & 3);
                    Vf[bh_base + (s >> 5) * 1024 + (dh >> 4) * 512
                       + (slot >> 3) * 128 + (dh & 15) * 8 + (slot & 7)] = o;
                } else {
                    size_t idx = bh_base + (s >> 4) * 512 + (dh >> 3) * 128
                                 + (s & 15) * 8 + (dh & 7);
                    if (z == 0) Qf[idx] = o; else Kf[idx] = o;
                }
            }
        }
}

// ---------------- flash pass: partial l and O' per (b,h,q16,ksplit) ----------------
// grid (S/64=32, H=8, B*KSPLIT=8), block 256 = 4 waves, one q16-tile per wave.
// All fragment loads lane-linear (unchanged from R4).
__global__ __launch_bounds__(256) void attn_flash(
    const __hip_bfloat16* __restrict__ Qf, const __hip_bfloat16* __restrict__ Kf,
    const __hip_bfloat16* __restrict__ Vf,
    float* __restrict__ Opart, float* __restrict__ Lpart)
{
    int tid = threadIdx.x, w = tid >> 6, lid = tid & 63, quad = lid >> 4, l15 = lid & 15;
    int h = blockIdx.y;
    int b = blockIdx.z >> 2, ks = blockIdx.z & 3;
    int q0 = (blockIdx.x * 4 + w) * 16;
    size_t bh_base = (size_t)(b * H_ + h) * (S_ * DH_);
    const __hip_bfloat16* Qp = Qf + bh_base + (q0 >> 4) * 512 + lid * 8;
    const __hip_bfloat16* Kp = Kf + bh_base + lid * 8;
    const __hip_bfloat16* Vp = Vf + bh_base + lid * 8;
    bf16x8 qf = *(const bf16x8*)Qp;                 // B: n=q (lane&15), k=dh
    f32x4 zacc = {};
    f32x4 oacc[2] = {};
    float lp0 = 0.f, lp1 = 0.f;

#pragma unroll 2
    for (int k0 = ks * KKEYS; k0 < (ks + 1) * KKEYS; k0 += 32) {
        bf16x8 kf0 = *(const bf16x8*)(Kp + (k0 >> 4) * 512);
        bf16x8 kf1 = *(const bf16x8*)(Kp + (k0 >> 4) * 512 + 512);
        f32x4 c0 = mfma_bf16(kf0, qf, zacc);   // keys k0+quad*4+r, q=l15
        f32x4 c1 = mfma_bf16(kf1, qf, zacc);   // keys k0+16+quad*4+r
        float e0[4], e1[4];
        for (int r = 0; r < 4; r++) {
            e0[r] = exp2f(c0[r]);
            e1[r] = exp2f(c1[r]);
        }
        lp0 += e0[0] + e0[1] + e0[2] + e0[3];
        lp1 += e1[0] + e1[1] + e1[2] + e1[3];
        union { bf16x8 v; __hip_bfloat162 h2[4]; } pu;
        pu.h2[0] = __float22bfloat162_rn(make_float2(e0[0], e0[1]));
        pu.h2[1] = __float22bfloat162_rn(make_float2(e0[2], e0[3]));
        pu.h2[2] = __float22bfloat162_rn(make_float2(e1[0], e1[1]));
        pu.h2[3] = __float22bfloat162_rn(make_float2(e1[2], e1[3]));
        bf16x8 vf0 = *(const bf16x8*)(Vp + (k0 >> 5) * 1024);
        bf16x8 vf1 = *(const bf16x8*)(Vp + (k0 >> 5) * 1024 + 512);
        oacc[0] = mfma_bf16(vf0, pu.v, oacc[0]);   // d 0..15
        oacc[1] = mfma_bf16(vf1, pu.v, oacc[1]);   // d 16..31
    }
    float lp = lp0 + lp1;
    lp += __shfl_xor(lp, 16);
    lp += __shfl_xor(lp, 32);

    size_t base = (size_t)((b * H_ + h) * KSPLIT + ks) * S_;
    if (lid < 16) Lpart[base + q0 + lid] = lp;
    f32x4* op = (f32x4*)(Opart + (base + q0 + l15) * DH_);
    op[quad] = oacc[0];
    op[quad + 4] = oacc[1];
}

// ---------------- combine: ctx = sum(O')/sum(l) -> fragment-linear hi/lo, invL ----------------
__global__ __launch_bounds__(256) void attn_combine(
    const float* __restrict__ Opart, const float* __restrict__ Lpart,
    __hip_bfloat16* __restrict__ cth, __hip_bfloat16* __restrict__ ctl,
    float* __restrict__ invL)
{
    int i = blockIdx.x * 256 + threadIdx.x;   // B*H*S*DH = 1,048,576
    int dh = i & 31;
    int s = (i >> 5) & (S_ - 1);
    int hb = i >> 16;                          // b*H+h in [0,16)
    float l = 0.f, o = 0.f;
#pragma unroll
    for (int ks = 0; ks < KSPLIT; ks++) {
        size_t base = (size_t)(hb * KSPLIT + ks) * S_ + s;
        l += Lpart[base];
        o += Opart[base * DH_ + dh];
    }
    float inv = 1.0f / l;
    float val = o * inv;
    int b = hb >> 3, h = hb & 7;
    // ctx is the A-operand of out_gemm: store fragment-linear at (m, c)
    size_t fi = fragidx(b * S_ + s, h * DH_ + dh);
    __hip_bfloat16 hv = __float2bfloat16(val);
    cth[fi] = hv;
    ctl[fi] = __float2bfloat16(val - __bfloat162float(hv));
    if (dh == 0) invL[hb * S_ + s] = inv;
}

// ---------------- attn write: head-mean probs, 16q x 256k per block ----------------
// grid (S/256=8, S/16=128, B=2) = 2048 blocks; wave w owns cols k0+w*64..+64.
__global__ __launch_bounds__(256) void attn_write(
    const __hip_bfloat16* __restrict__ Qf, const __hip_bfloat16* __restrict__ Kf,
    const float* __restrict__ invL, float* __restrict__ attn)
{
    __shared__ float invbuf[H_ * 16];
    int tid = threadIdx.x, w = tid >> 6, lid = tid & 63, quad = lid >> 4, l15 = lid & 15;
    int b = blockIdx.z;
    int q0 = blockIdx.y * 16;
    int k0 = blockIdx.x * 256 + w * 64;
    if (tid < 128) {
        int h = tid >> 4, r = tid & 15;
        invbuf[tid] = invL[(b * H_ + h) * S_ + q0 + r] * 0.125f;  // fold 1/H
    }
    __syncthreads();
    f32x4 zacc = {};
    float psum[4][4] = {};
    for (int h = 0; h < H_; h++) {
        size_t bh_base = (size_t)(b * H_ + h) * (S_ * DH_);
        bf16x8 qf = *(const bf16x8*)(Qf + bh_base + (q0 >> 4) * 512 + lid * 8);
        const __hip_bfloat16* Kp = Kf + bh_base + (k0 >> 4) * 512 + lid * 8;
        float il[4];
        for (int r = 0; r < 4; r++) il[r] = invbuf[h * 16 + quad * 4 + r];
        for (int nt = 0; nt < 4; nt++) {
            bf16x8 kf = *(const bf16x8*)(Kp + nt * 512);
            f32x4 c = mfma_bf16(qf, kf, zacc);  // C: row=q (quad*4+r), col=key (l15)
            for (int r = 0; r < 4; r++)
                psum[nt][r] += exp2f(c[r]) * il[r];
        }
    }
    for (int nt = 0; nt < 4; nt++)
        for (int r = 0; r < 4; r++)
            attn[(size_t)(b * S_ + q0 + quad * 4 + r) * S_ + k0 + nt * 16 + l15] =
                psum[nt][r];
}

// ---------------- output projection: out = ctx @ wc^T + bc (fp32 out) ----------------
// grid (NROW/64=64, 4), block 256 (4 waves, 2x2 wave tiles of 32x32).
__global__ __launch_bounds__(256) void out_gemm(
    const __hip_bfloat16* __restrict__ ch, const __hip_bfloat16* __restrict__ cl,
    const __hip_bfloat16* __restrict__ wh, const __hip_bfloat16* __restrict__ wl,
    const float* __restrict__ bias, float* __restrict__ out)
{
    int tid = threadIdx.x;
    int w = tid >> 6, lid = tid & 63, quad = lid >> 4, l15 = lid & 15;
    int row0 = blockIdx.x * 64 + (w >> 1) * 32;
    int col0 = blockIdx.y * 64 + (w & 1) * 32;

    f32x4 acc[2][2] = {};
#pragma unroll
    for (int k0 = 0; k0 < 256; k0 += 32) {
        bf16x8 ah[2], al[2], bh[2], bl[2];
        for (int mi = 0; mi < 2; mi++) {
            size_t ro = (size_t)((row0 + mi * 16) >> 4) * 4096 + (k0 >> 5) * 512 + lid * 8;
            ah[mi] = *(const bf16x8*)(ch + ro);
            al[mi] = *(const bf16x8*)(cl + ro);
        }
        for (int ni = 0; ni < 2; ni++) {
            size_t co = (size_t)((col0 + ni * 16) >> 4) * 4096 + (k0 >> 5) * 512 + lid * 8;
            bh[ni] = *(const bf16x8*)(wh + co);
            bl[ni] = *(const bf16x8*)(wl + co);
        }
        for (int mi = 0; mi < 2; mi++)
            for (int ni = 0; ni < 2; ni++) {
                acc[mi][ni] = mfma_bf16(ah[mi], bh[ni], acc[mi][ni]);
                acc[mi][ni] = mfma_bf16(ah[mi], bl[ni], acc[mi][ni]);
                acc[mi][ni] = mfma_bf16(al[mi], bh[ni], acc[mi][ni]);
            }
    }
    for (int mi = 0; mi < 2; mi++)
        for (int ni = 0; ni < 2; ni++) {
            int col = col0 + ni * 16 + l15;
            float bvl = bias[col];
            for (int r = 0; r < 4; r++) {
                int row = row0 + mi * 16 + quad * 4 + r;
                out[(size_t)row * 256 + col] = acc[mi][ni][r] + bvl;
            }
        }
}

extern "C" void kernel_launch(void* const* d_in, const int* in_sizes, int n_in,
                              void* d_out, int out_size, void* d_ws, size_t ws_size,
                              hipStream_t stream) {
    const float* x  = (const float*)d_in[0];
    const float* wq = (const float*)d_in[1];
    const float* bq = (const float*)d_in[2];
    const float* wk = (const float*)d_in[3];
    const float* bk = (const float*)d_in[4];
    const float* wv = (const float*)d_in[5];
    const float* bv = (const float*)d_in[6];
    const float* wc = (const float*)d_in[7];
    const float* bc = (const float*)d_in[8];

    char* ws = (char*)d_ws;
    const size_t MB = 1u << 20;
    const size_t KB128 = 128u * 1024u;
    __hip_bfloat16* xh  = (__hip_bfloat16*)(ws + 0 * MB);
    __hip_bfloat16* xl  = (__hip_bfloat16*)(ws + 2 * MB);
    __hip_bfloat16* wqh = (__hip_bfloat16*)(ws + 4 * MB + 0 * KB128);
    __hip_bfloat16* wql = (__hip_bfloat16*)(ws + 4 * MB + 1 * KB128);
    __hip_bfloat16* wkh = (__hip_bfloat16*)(ws + 4 * MB + 2 * KB128);
    __hip_bfloat16* wkl = (__hip_bfloat16*)(ws + 4 * MB + 3 * KB128);
    __hip_bfloat16* wvh = (__hip_bfloat16*)(ws + 4 * MB + 4 * KB128);
    __hip_bfloat16* wvl = (__hip_bfloat16*)(ws + 4 * MB + 5 * KB128);
    __hip_bfloat16* wch = (__hip_bfloat16*)(ws + 4 * MB + 6 * KB128);
    __hip_bfloat16* wcl = (__hip_bfloat16*)(ws + 4 * MB + 7 * KB128);
    __hip_bfloat16* Qfb = (__hip_bfloat16*)(ws + 5 * MB);
    __hip_bfloat16* Kfb = (__hip_bfloat16*)(ws + 7 * MB);
    __hip_bfloat16* Vfb = (__hip_bfloat16*)(ws + 9 * MB);
    __hip_bfloat16* cth = (__hip_bfloat16*)(ws + 11 * MB);
    __hip_bfloat16* ctl = (__hip_bfloat16*)(ws + 13 * MB);
    float* Opart = (float*)(ws + 15 * MB);                    // 16 MB (KSPLIT=4)
    float* Lpart = (float*)(ws + 31 * MB);                    // 512 KB
    float* invL  = (float*)(ws + 31 * MB + 512 * 1024);       // 128 KB

    float* outp  = (float*)d_out;
    float* attnp = outp + (size_t)NROW * D_;  // outputs concatenated: out, attention

    hipLaunchKernelGGL(split_all, dim3(1280), dim3(256), 0, stream,
                       (const float4*)x, (const float4*)wq, (const float4*)wk,
                       (const float4*)wv, (const float4*)wc,
                       (ushort4*)xh, (ushort4*)xl,
                       (ushort4*)wqh, (ushort4*)wql, (ushort4*)wkh, (ushort4*)wkl,
                       (ushort4*)wvh, (ushort4*)wvl, (ushort4*)wch, (ushort4*)wcl);

    hipLaunchKernelGGL(qkv_gemm, dim3(NROW / 64, 4, 3), dim3(256), 0, stream,
                       xh, xl, wqh, wql, wkh, wkl, wvh, wvl, bq, bk, bv, Qfb, Kfb, Vfb);

    hipLaunchKernelGGL(attn_flash, dim3(S_ / 64, H_, B_ * KSPLIT), dim3(256), 0, stream,
                       Qfb, Kfb, Vfb, Opart, Lpart);

    hipLaunchKernelGGL(attn_combine, dim3(4096), dim3(256), 0, stream,
                       Opart, Lpart, cth, ctl, invL);

    hipLaunchKernelGGL(attn_write, dim3(S_ / 256, S_ / 16, B_), dim3(256), 0, stream,
                       Qfb, Kfb, invL, attnp);

    hipLaunchKernelGGL(out_gemm, dim3(NROW / 64, 4), dim3(256), 0, stream,
                       cth, ctl, wch, wcl, bc, outp);
}